// Round 1
// baseline (108.572 us; speedup 1.0000x reference)
//
#include <hip/hip_runtime.h>
#include <math.h>

// ColBERT pairwise late-interaction score, fused single kernel.
//
// out[b,o] = scale/sqrt(Lq*Lk) * sum_i log(sum_j exp(alpha * qn[b,i].kn[o,j]))/alpha
// with masking; entire row b is exactly zero if any q_mask[b,i] is set
// (reference's isfinite guard after the Lq-sum), so ~97% of blocks early-exit.
//
// Numerics: S <= 1 (cosine), so alpha*S <= 12 -> exp never overflows; no
// max-subtraction pass required. Masked j contribute exp(-inf)=0.

#define ALPHA 12.0f

constexpr int B_  = 64;
constexpr int LQ  = 32;
constexpr int O_  = 128;
constexpr int LK  = 256;
constexpr int D_  = 128;

__global__ __launch_bounds__(256)
void colbert_pairwise_kernel(const float* __restrict__ q,      // [B, Lq, D]
                             const float* __restrict__ k,      // [O, Lk, D]
                             const int*  __restrict__ q_mask,  // [B, Lq] 0/1
                             const int*  __restrict__ k_mask,  // [O, Lk] 0/1
                             const float* __restrict__ logit_scale, // [1]
                             float* __restrict__ out)          // [B, O]
{
    const int o = blockIdx.x;
    const int b = blockIdx.y;
    const int t = threadIdx.x;

    // ---- per-b early exit: any masked q position zeroes the whole row ----
    // every wave covers rows 0..31 (twice), so ballot is block-uniform
    int qm = q_mask[b * LQ + (t & 31)];
    unsigned long long anyq = __ballot(qm != 0);
    if (anyq != 0ULL) {
        if (t == 0) out[b * O_ + o] = 0.0f;   // d_out is poisoned; must write
        return;
    }

    __shared__ float4 qs[LQ * D_ / 4];   // 32x128 fp32 = 16 KiB
    __shared__ float  rq[LQ];            // 1/||q_row||
    __shared__ float  partial[4][LQ];    // per-wave row partial sums

    // ---- stage q[b] into LDS (coalesced float4) ----
    const float4* qg = (const float4*)(q + (size_t)b * LQ * D_);
    #pragma unroll
    for (int u = 0; u < 4; ++u)
        qs[t + u * 256] = qg[t + u * 256];
    __syncthreads();

    // ---- row norms (threads 0..31, one row each, LDS reads) ----
    if (t < LQ) {
        float ss = 0.0f;
        #pragma unroll
        for (int d4 = 0; d4 < D_ / 4; ++d4) {
            float4 v = qs[t * (D_ / 4) + d4];
            ss = fmaf(v.x, v.x, ss);
            ss = fmaf(v.y, v.y, ss);
            ss = fmaf(v.z, v.z, ss);
            ss = fmaf(v.w, v.w, ss);
        }
        rq[t] = 1.0f / fmaxf(sqrtf(ss), 1e-12f);
    }
    __syncthreads();

    // ---- each thread owns one k column j = t; accumulate 32 dots ----
    const int j = t;
    const float4* kg = (const float4*)(k + ((size_t)o * LK + j) * D_);

    float dot[LQ];
    #pragma unroll
    for (int i = 0; i < LQ; ++i) dot[i] = 0.0f;
    float ksq = 0.0f;

    #pragma unroll 1
    for (int d4 = 0; d4 < D_ / 4; ++d4) {
        float4 kv = kg[d4];
        ksq = fmaf(kv.x, kv.x, ksq);
        ksq = fmaf(kv.y, kv.y, ksq);
        ksq = fmaf(kv.z, kv.z, ksq);
        ksq = fmaf(kv.w, kv.w, ksq);
        #pragma unroll
        for (int i = 0; i < LQ; ++i) {
            float4 qv = qs[i * (D_ / 4) + d4];   // uniform addr -> LDS broadcast
            dot[i] = fmaf(qv.x, kv.x, dot[i]);
            dot[i] = fmaf(qv.y, kv.y, dot[i]);
            dot[i] = fmaf(qv.z, kv.z, dot[i]);
            dot[i] = fmaf(qv.w, kv.w, dot[i]);
        }
    }

    const float rk = 1.0f / fmaxf(sqrtf(ksq), 1e-12f);
    const bool  kvalid = (k_mask[o * LK + j] == 0);

    // ---- exp + reduce over j (256 threads) per row i ----
    const int lane = t & 63;
    const int wv   = t >> 6;
    #pragma unroll
    for (int i = 0; i < LQ; ++i) {
        float e = kvalid ? __expf(ALPHA * dot[i] * rq[i] * rk) : 0.0f;
        #pragma unroll
        for (int off = 32; off > 0; off >>= 1)
            e += __shfl_xor(e, off);
        if (lane == 0) partial[wv][i] = e;
    }
    __syncthreads();

    // ---- final: wave 0, one thread per row; then reduce over rows ----
    if (t < LQ) {
        float rs = partial[0][t] + partial[1][t] + partial[2][t] + partial[3][t];
        bool  rowzero = (rs <= 0.0f);            // all k masked -> -inf -> out 0
        float lg = __logf(fmaxf(rs, 1e-38f));

        float tot = lg;
        #pragma unroll
        for (int off = 16; off > 0; off >>= 1)
            tot += __shfl_xor(tot, off);
        unsigned long long zb = __ballot(rowzero);  // inactive lanes contribute 0

        if (t == 0) {
            float res = 0.0f;
            if (zb == 0ULL) {
                float scale = fminf(__expf(logit_scale[0]), 100.0f);
                float inv_ln = 1.0f / (sqrtf((float)(LQ * LK)) + 1e-6f);
                res = (tot / ALPHA) * inv_ln * scale;
            }
            out[b * O_ + o] = res;
        }
    }
}

extern "C" void kernel_launch(void* const* d_in, const int* in_sizes, int n_in,
                              void* d_out, int out_size, void* d_ws, size_t ws_size,
                              hipStream_t stream) {
    const float* q           = (const float*)d_in[0];
    const float* k           = (const float*)d_in[1];
    const int*   q_mask      = (const int*)d_in[2];
    const int*   k_mask      = (const int*)d_in[3];
    const float* logit_scale = (const float*)d_in[4];
    float* out = (float*)d_out;

    dim3 grid(O_, B_);   // one block per (o, b)
    colbert_pairwise_kernel<<<grid, 256, 0, stream>>>(q, k, q_mask, k_mask,
                                                      logit_scale, out);
}

// Round 2
// 96.019 us; speedup vs baseline: 1.1307x; 1.1307x over previous
//
#include <hip/hip_runtime.h>
#include <math.h>

// ColBERT pairwise late-interaction score, fused single kernel.
//
// out[b,o] = scale/sqrt(Lq*Lk) * sum_i log(sum_j exp(alpha * qn[b,i].kn[o,j]))/alpha
// Row b is exactly zero if any q_mask[b,i] is set (reference's isfinite guard
// after the Lq-sum) -> ~97% of (b,o) blocks early-exit after one ballot.
//
// Live-block design (R2): 256 threads = 4 waves. Wave w owns rows [8w,8w+8);
// each thread owns 4 k-columns (j = c*64 + lane). This cuts the LDS q-broadcast
// 4x vs. the R1 layout (waves no longer duplicate each other's q reads) and
// shrinks per-thread accumulators to dot[8][4] = 32 VGPRs (R1's dot[32] was
// spilling: 28 allocated VGPRs @ 44us).
//
// Numerics: S <= 1 (cosine), alpha*S <= 12 -> exp never overflows, no
// max-subtraction needed. Masked j contribute exactly 0; valid j contribute
// >= e^-12, so rowsum==0 <=> row fully masked (-inf -> zero output).

#define ALPHA 12.0f

constexpr int B_  = 64;
constexpr int LQ  = 32;
constexpr int O_  = 128;
constexpr int LK  = 256;
constexpr int D_  = 128;

__global__ __launch_bounds__(256, 1)
void colbert_pairwise_kernel(const float* __restrict__ q,      // [B, Lq, D]
                             const float* __restrict__ k,      // [O, Lk, D]
                             const int*  __restrict__ q_mask,  // [B, Lq] 0/1
                             const int*  __restrict__ k_mask,  // [O, Lk] 0/1
                             const float* __restrict__ logit_scale, // [1]
                             float* __restrict__ out)          // [B, O]
{
    const int o    = blockIdx.x;
    const int b    = blockIdx.y;
    const int t    = threadIdx.x;
    const int lane = t & 63;
    const int w    = t >> 6;          // wave id 0..3

    // ---- per-b early exit: any masked q position zeroes the whole row ----
    // block-uniform decision: every wave ballots the same 32 values
    int qm = q_mask[b * LQ + (t & 31)];
    if (__ballot(qm != 0) != 0ULL) {
        if (t == 0) out[b * O_ + o] = 0.0f;   // d_out is poisoned; must write
        return;
    }

    __shared__ float4 qs[LQ * D_ / 4];   // [i][d4] at i*32+d4 ; 16 KiB
    __shared__ float  rq[LQ];            // 1/||q_row||
    __shared__ float  wsum[4];
    __shared__ int    wbad[4];

    // ---- stage q[b] into LDS (coalesced float4) ----
    const float4* qg = (const float4*)(q + (size_t)b * LQ * D_);
    #pragma unroll
    for (int u = 0; u < 4; ++u)
        qs[t + u * 256] = qg[t + u * 256];
    __syncthreads();

    // ---- row norms: threads 0..31, skewed d4 order to avoid bank conflicts --
    if (t < LQ) {
        float ss = 0.0f;
        #pragma unroll
        for (int dd = 0; dd < D_ / 4; ++dd) {
            int d4 = (dd + t) & 31;              // skew: lanes hit different banks
            float4 v = qs[t * 32 + d4];
            ss = fmaf(v.x, v.x, ss);
            ss = fmaf(v.y, v.y, ss);
            ss = fmaf(v.z, v.z, ss);
            ss = fmaf(v.w, v.w, ss);
        }
        rq[t] = 1.0f / fmaxf(sqrtf(ss), 1e-12f);
    }
    __syncthreads();

    const int i0 = w * 8;                         // this wave's row range

    // ---- per-thread column set: j = c*64 + lane ----
    const float4* kg[4];
    bool kvalid[4];
    #pragma unroll
    for (int c = 0; c < 4; ++c) {
        int j = c * 64 + lane;
        kg[c]     = (const float4*)(k + ((size_t)o * LK + j) * D_);
        kvalid[c] = (k_mask[o * LK + j] == 0);
    }

    float dot[8][4];
    #pragma unroll
    for (int il = 0; il < 8; ++il)
        #pragma unroll
        for (int c = 0; c < 4; ++c) dot[il][c] = 0.0f;
    float ksq[4] = {0.0f, 0.0f, 0.0f, 0.0f};

    #pragma unroll 2
    for (int d4 = 0; d4 < D_ / 4; ++d4) {
        float4 kv[4];
        #pragma unroll
        for (int c = 0; c < 4; ++c) kv[c] = kg[c][d4];
        #pragma unroll
        for (int c = 0; c < 4; ++c) {
            ksq[c] = fmaf(kv[c].x, kv[c].x, ksq[c]);
            ksq[c] = fmaf(kv[c].y, kv[c].y, ksq[c]);
            ksq[c] = fmaf(kv[c].z, kv[c].z, ksq[c]);
            ksq[c] = fmaf(kv[c].w, kv[c].w, ksq[c]);
        }
        #pragma unroll
        for (int il = 0; il < 8; ++il) {
            float4 qv = qs[(i0 + il) * 32 + d4];   // uniform addr -> broadcast
            #pragma unroll
            for (int c = 0; c < 4; ++c) {
                dot[il][c] = fmaf(qv.x, kv[c].x, dot[il][c]);
                dot[il][c] = fmaf(qv.y, kv[c].y, dot[il][c]);
                dot[il][c] = fmaf(qv.z, kv[c].z, dot[il][c]);
                dot[il][c] = fmaf(qv.w, kv[c].w, dot[il][c]);
            }
        }
    }

    float rk[4];
    #pragma unroll
    for (int c = 0; c < 4; ++c)
        rk[c] = 1.0f / fmaxf(sqrtf(ksq[c]), 1e-12f);

    // ---- exp + full-row reduce (each wave's 64 lanes own all 256 j) ----
    float wtot = 0.0f;
    int   wbadf = 0;
    #pragma unroll
    for (int il = 0; il < 8; ++il) {
        float r = rq[i0 + il];
        float e = 0.0f;
        #pragma unroll
        for (int c = 0; c < 4; ++c)
            if (kvalid[c]) e += __expf(ALPHA * dot[il][c] * r * rk[c]);
        #pragma unroll
        for (int off = 32; off > 0; off >>= 1)
            e += __shfl_xor(e, off);
        wbadf |= (e <= 0.0f);                    // row fully k-masked -> -inf
        wtot  += __logf(fmaxf(e, 1e-38f));       // same value on all lanes
    }
    if (lane == 0) { wsum[w] = wtot; wbad[w] = wbadf; }
    __syncthreads();

    if (t == 0) {
        float res = 0.0f;
        if ((wbad[0] | wbad[1] | wbad[2] | wbad[3]) == 0) {
            float tot = wsum[0] + wsum[1] + wsum[2] + wsum[3];
            float scale  = fminf(__expf(logit_scale[0]), 100.0f);
            float inv_ln = 1.0f / (sqrtf((float)(LQ * LK)) + 1e-6f);
            res = (tot / ALPHA) * inv_ln * scale;
        }
        out[b * O_ + o] = res;
    }
}

extern "C" void kernel_launch(void* const* d_in, const int* in_sizes, int n_in,
                              void* d_out, int out_size, void* d_ws, size_t ws_size,
                              hipStream_t stream) {
    const float* q           = (const float*)d_in[0];
    const float* k           = (const float*)d_in[1];
    const int*   q_mask      = (const int*)d_in[2];
    const int*   k_mask      = (const int*)d_in[3];
    const float* logit_scale = (const float*)d_in[4];
    float* out = (float*)d_out;

    dim3 grid(O_, B_);   // one block per (o, b)
    colbert_pairwise_kernel<<<grid, 256, 0, stream>>>(q, k, q_mask, k_mask,
                                                      logit_scale, out);
}

// Round 3
// 78.733 us; speedup vs baseline: 1.3790x; 1.2196x over previous
//
#include <hip/hip_runtime.h>
#include <math.h>

// ColBERT pairwise late-interaction score. Three-phase structure:
//   phase 0: zero out + compute live-b list (any q_mask[b,i] -> whole row b is
//            zero via the reference's isfinite guard; with p=0.1 over 32
//            positions only ~2-3 of 64 b's are live)
//   phase 1: main kernel over M*128 live (b,o) tasks on a fixed 512-block
//            grid — dead pairs cost nothing (no dispatch, no LDS residency).
// Live task = 32x256x128 cosine-sim matmul -> MFMA f16 (fp32 has no MFMA on
// CDNA4; f16 rounding ~1e-3 final abs error vs 5.1e-2 threshold).
// R2 lesson: per-lane k column loads (stride 512 B) cost ~64 lines/instr in
// the TA (~14 us/block). Here k is staged coalesced to LDS once per task.

#define ALPHA 12.0f

constexpr int B_  = 64;
constexpr int LQ  = 32;
constexpr int O_  = 128;
constexpr int LK  = 256;
constexpr int D_  = 128;
constexpr int LDH = D_ + 8;        // f16 row stride 136 (272 B): +16 B pad makes
                                   // MFMA fragment b128 reads spread all 8 bank
                                   // quads (unpadded 256 B stride = 1 quad = 8x)

typedef _Float16 half8 __attribute__((ext_vector_type(8)));
typedef _Float16 half4_t __attribute__((ext_vector_type(4)));
typedef float    f32x4 __attribute__((ext_vector_type(4)));

// ---------------- phase 0: liveness compaction + out zeroing ----------------
__global__ __launch_bounds__(256)
void prep_kernel(const int* __restrict__ q_mask,   // [B, Lq] 0/1
                 float* __restrict__ out,          // [B, O] -> zeroed
                 int* __restrict__ ws)             // ws[0]=M, ws[1..]=live b's
{
    __shared__ int anyb[B_];
    const int t = threadIdx.x;
    if (t < B_) anyb[t] = 0;
    __syncthreads();
    #pragma unroll
    for (int r = 0; r < 8; ++r) {
        int idx = t + 256 * r;                    // 0..2047 over [B][Lq]
        if (q_mask[idx] != 0) atomicOr(&anyb[idx >> 5], 1);
    }
    __syncthreads();
    // zero entire output (live rows get overwritten by main kernel)
    float4* o4 = (float4*)out;
    #pragma unroll
    for (int r = 0; r < 8; ++r)
        o4[t + 256 * r] = make_float4(0.f, 0.f, 0.f, 0.f);
    // wave 0 compacts the live list via ballot
    if (t < 64) {
        bool live = (anyb[t] == 0);
        unsigned long long m = __ballot(live);
        if (live) {
            int rank = __popcll(m & ((1ull << t) - 1ull));
            ws[1 + rank] = t;
        }
        if (t == 0) ws[0] = (int)__popcll(m);
    }
}

// ---------------- phase 1: live (b,o) tasks, MFMA f16 ----------------
__global__ __launch_bounds__(256, 2)
void colbert_main_kernel(const float* __restrict__ q,       // [B, Lq, D]
                         const float* __restrict__ k,       // [O, Lk, D]
                         const int*  __restrict__ k_mask,   // [O, Lk]
                         const float* __restrict__ logit_scale,
                         const int*  __restrict__ ws,
                         float* __restrict__ out)
{
    __shared__ _Float16 kl[LK][LDH];   // 69632 B
    __shared__ _Float16 ql[LQ][LDH];   //  8704 B
    __shared__ float rk[LK];           // 1/||k_j||
    __shared__ float bj[LK];           // 0 or -1e30 (masked j -> exp -> 0)
    __shared__ float rqa[LQ];          // ALPHA/||q_i||
    __shared__ float part[2][LQ];      // per-col-half row exp-sums

    const int t     = threadIdx.x;
    const int lane  = t & 63;
    const int w     = t >> 6;
    const int row16 = lane & 15;       // MFMA m/n index
    const int quad  = lane >> 4;       // MFMA k-quad / C-row quad

    const int M     = ws[0];
    const int ntask = M * O_;

    for (int task = blockIdx.x; task < ntask; task += gridDim.x) {
        __syncthreads();               // protect LDS reuse across tasks
        const int b = ws[1 + (task >> 7)];
        const int o = task & (O_ - 1);

        // ---- stage q[b] (fp32 global, coalesced) -> f16 LDS ----
        const float4* qg = (const float4*)(q + (size_t)b * LQ * D_);
        #pragma unroll
        for (int r = 0; r < 4; ++r) {
            int idx = t + 256 * r;                 // float4 index over [32][32]
            float4 v = qg[idx];
            int i = idx >> 5, c4 = idx & 31;
            half4_t h;
            h[0] = (_Float16)v.x; h[1] = (_Float16)v.y;
            h[2] = (_Float16)v.z; h[3] = (_Float16)v.w;
            *(half4_t*)&ql[i][c4 * 4] = h;
        }
        // ---- stage k[o] (128 KB, coalesced) -> f16 LDS ----
        const float4* kg = (const float4*)(k + (size_t)o * LK * D_);
        #pragma unroll
        for (int r = 0; r < 32; ++r) {
            int idx = t + 256 * r;                 // float4 index over [256][32]
            float4 v = kg[idx];
            int j = idx >> 5, c4 = idx & 31;
            half4_t h;
            h[0] = (_Float16)v.x; h[1] = (_Float16)v.y;
            h[2] = (_Float16)v.z; h[3] = (_Float16)v.w;
            *(half4_t*)&kl[j][c4 * 4] = h;
        }
        __syncthreads();

        // ---- norms from f16 LDS (error ~1e-3 relative, fine vs 2% thr) ----
        if (t < LQ) {
            float ss = 0.f;
            #pragma unroll
            for (int p = 0; p < 16; ++p) {
                half8 h = *(const half8*)&ql[t][p * 8];
                #pragma unroll
                for (int e = 0; e < 8; ++e) {
                    float x = (float)h[e];
                    ss = fmaf(x, x, ss);
                }
            }
            rqa[t] = ALPHA / fmaxf(sqrtf(ss), 1e-12f);
        }
        {   // each thread owns one k row j = t
            float ss = 0.f;
            #pragma unroll
            for (int p = 0; p < 16; ++p) {
                half8 h = *(const half8*)&kl[t][p * 8];
                #pragma unroll
                for (int e = 0; e < 8; ++e) {
                    float x = (float)h[e];
                    ss = fmaf(x, x, ss);
                }
            }
            rk[t] = 1.0f / fmaxf(sqrtf(ss), 1e-12f);
            bj[t] = (k_mask[o * LK + t] != 0) ? -1e30f : 0.0f;
        }
        __syncthreads();

        // ---- MFMA: wave w -> rows [16*(w>>1), +16), cols [(w&1)*128, +128) ----
        const int i0 = (w >> 1) * 16;
        const int j0 = (w & 1) * 128;

        half8 afrag[4];
        #pragma unroll
        for (int kk = 0; kk < 4; ++kk)
            afrag[kk] = *(const half8*)&ql[i0 + row16][kk * 32 + quad * 8];

        float rqv[4];
        #pragma unroll
        for (int rg = 0; rg < 4; ++rg)
            rqv[rg] = rqa[i0 + quad * 4 + rg];

        float esum[4] = {0.f, 0.f, 0.f, 0.f};
        #pragma unroll
        for (int c = 0; c < 8; ++c) {
            const int jt = j0 + c * 16;
            f32x4 acc = {0.f, 0.f, 0.f, 0.f};
            #pragma unroll
            for (int kk = 0; kk < 4; ++kk) {
                half8 bfrag = *(const half8*)&kl[jt + row16][kk * 32 + quad * 8];
                acc = __builtin_amdgcn_mfma_f32_16x16x32_f16(afrag[kk], bfrag,
                                                             acc, 0, 0, 0);
            }
            // C layout: col = lane&15 (j), row = quad*4+reg (i)  [m89/m91]
            const float rkj = rk[jt + row16];
            const float bb  = bj[jt + row16];
            #pragma unroll
            for (int rg = 0; rg < 4; ++rg)
                esum[rg] += __expf(acc[rg] * rqv[rg] * rkj + bb);
        }
        // reduce over the 16 col-lanes of each row
        #pragma unroll
        for (int rg = 0; rg < 4; ++rg) {
            float e = esum[rg];
            e += __shfl_xor(e, 1);
            e += __shfl_xor(e, 2);
            e += __shfl_xor(e, 4);
            e += __shfl_xor(e, 8);
            esum[rg] = e;
        }
        if (row16 == 0) {
            #pragma unroll
            for (int rg = 0; rg < 4; ++rg)
                part[w & 1][i0 + quad * 4 + rg] = esum[rg];
        }
        __syncthreads();

        // ---- final: wave 0 combines col-halves, log, row-sum, scale ----
        if (t < 64) {
            float s = 0.f, lse = 0.f;
            bool badrow = false;
            if (t < LQ) {
                s = part[0][t] + part[1][t];
                badrow = (s <= 0.f);               // row fully k-masked -> -inf
                lse = __logf(fmaxf(s, 1e-38f));
            }
            unsigned long long zb = __ballot(badrow);
            float tot = lse;                        // lanes >=32 contribute 0
            tot += __shfl_xor(tot, 32);
            tot += __shfl_xor(tot, 16);
            tot += __shfl_xor(tot, 8);
            tot += __shfl_xor(tot, 4);
            tot += __shfl_xor(tot, 2);
            tot += __shfl_xor(tot, 1);
            if (t == 0) {
                float res = 0.f;
                if (zb == 0ULL) {
                    float scale  = fminf(__expf(logit_scale[0]), 100.0f);
                    float inv_ln = 1.0f / (sqrtf((float)(LQ * LK)) + 1e-6f);
                    res = (tot * (1.0f / ALPHA)) * inv_ln * scale;
                }
                out[b * O_ + o] = res;
            }
        }
    }
}

extern "C" void kernel_launch(void* const* d_in, const int* in_sizes, int n_in,
                              void* d_out, int out_size, void* d_ws, size_t ws_size,
                              hipStream_t stream) {
    const float* q           = (const float*)d_in[0];
    const float* k           = (const float*)d_in[1];
    const int*   q_mask      = (const int*)d_in[2];
    const int*   k_mask      = (const int*)d_in[3];
    const float* logit_scale = (const float*)d_in[4];
    float* out = (float*)d_out;
    int*   ws  = (int*)d_ws;

    prep_kernel<<<1, 256, 0, stream>>>(q_mask, out, ws);
    colbert_main_kernel<<<512, 256, 0, stream>>>(q, k, k_mask, logit_scale,
                                                 ws, out);
}

// Round 4
// 76.112 us; speedup vs baseline: 1.4265x; 1.0344x over previous
//
#include <hip/hip_runtime.h>
#include <math.h>

// ColBERT pairwise late-interaction score — SINGLE fused kernel (R4).
//
// out[b,o] = scale/sqrt(Lq*Lk) * sum_i log(sum_j exp(alpha*qn[b,i].kn[o,j]))/alpha
// Row b is exactly zero if any q_mask[b,i] is set (reference's isfinite guard
// after the Lq-sum). With p=0.1 over 32 positions only ~2-3 of 64 b's are live.
//
// R4 structure: grid = 128 blocks, one per o. Each block:
//   1. recomputes b-liveness from q_mask (8 KB, L2-hit — cheaper than a
//      separate prep kernel + launch dependency, which cost ~5 us in R3)
//   2. zeroes out[b,o] for dead b's
//   3. stages k[o] -> f16 LDS ONCE (R3's (b,o)-task design staged it M times:
//      M*16 MB vs 16 MB total k traffic)
//   4. loops over the M live b's: stage q[b], norms, MFMA f16, exp/log reduce.
//
// Numerics: S <= 1 (cosine), alpha*S <= 12 -> exp never overflows; masked j
// add -1e30 before exp -> exact 0. f16 input rounding ~1e-3 final error vs
// 5.1e-2 threshold (R3 passed with identical math).

#define ALPHA 12.0f

constexpr int B_  = 64;
constexpr int LQ  = 32;
constexpr int O_  = 128;
constexpr int LK  = 256;
constexpr int D_  = 128;
constexpr int LDH = D_ + 8;        // f16 row stride 136 (272 B): +16 B pad keeps
                                   // MFMA b128 fragment reads spread over banks

typedef _Float16 half8   __attribute__((ext_vector_type(8)));
typedef _Float16 half4_t __attribute__((ext_vector_type(4)));
typedef float    f32x4   __attribute__((ext_vector_type(4)));

__global__ __launch_bounds__(256, 1)
void colbert_fused_kernel(const float* __restrict__ q,       // [B, Lq, D]
                          const float* __restrict__ k,       // [O, Lk, D]
                          const int*  __restrict__ q_mask,   // [B, Lq] 0/1
                          const int*  __restrict__ k_mask,   // [O, Lk] 0/1
                          const float* __restrict__ logit_scale,
                          float* __restrict__ out)           // [B, O]
{
    __shared__ _Float16 kl[LK][LDH];   // 69632 B
    __shared__ _Float16 ql[LQ][LDH];   //  8704 B
    __shared__ float rk[LK];           // 1/||k_j||
    __shared__ float bj[LK];           // 0 or -1e30 (masked j)
    __shared__ float rqa[LQ];          // ALPHA/||q_i||
    __shared__ float part[2][LQ];      // per-col-half row exp-sums
    __shared__ int   deadf[B_];
    __shared__ int   lbm[B_ + 1];      // [0]=M, [1+m]=live b

    const int o     = blockIdx.x;
    const int t     = threadIdx.x;
    const int lane  = t & 63;
    const int w     = t >> 6;
    const int row16 = lane & 15;       // MFMA m/n index
    const int quad  = lane >> 4;       // MFMA k-quad / C-row quad

    // ---- 1. liveness: thread t scans q_mask[8t..8t+8) for b = t>>2 ----
    {
        const int4* qm4 = (const int4*)q_mask;
        int4 a0 = qm4[t * 2], a1 = qm4[t * 2 + 1];
        int any = a0.x | a0.y | a0.z | a0.w | a1.x | a1.y | a1.z | a1.w;
        any |= __shfl_xor(any, 1);     // quad of 4 lanes covers one b
        any |= __shfl_xor(any, 2);
        if ((t & 3) == 0) {
            int b = t >> 2;
            deadf[b] = any;
            if (any) out[b * O_ + o] = 0.0f;    // 2. dead rows -> exact zero
        }
    }
    __syncthreads();
    // wave 0 compacts the live list
    if (t < 64) {
        bool live = (deadf[t] == 0);
        unsigned long long m = __ballot(live);
        if (live) {
            int rank = __popcll(m & ((1ull << t) - 1ull));
            lbm[1 + rank] = t;
        }
        if (t == 0) lbm[0] = (int)__popcll(m);
    }
    __syncthreads();
    const int M = lbm[0];
    if (M == 0) return;                // block-uniform

    // ---- 3. stage k[o] (128 KB fp32, coalesced) -> f16 LDS, once ----
    {
        const float4* kg = (const float4*)(k + (size_t)o * LK * D_);
        #pragma unroll 8
        for (int r = 0; r < 32; ++r) {
            int idx = t + 256 * r;                 // float4 index over [256][32]
            float4 v = kg[idx];
            int j = idx >> 5, c4 = idx & 31;
            half4_t h;
            h[0] = (_Float16)v.x; h[1] = (_Float16)v.y;
            h[2] = (_Float16)v.z; h[3] = (_Float16)v.w;
            *(half4_t*)&kl[j][c4 * 4] = h;
        }
    }
    __syncthreads();
    {   // k norms + mask bias: thread t owns row j = t
        float ss = 0.f;
        #pragma unroll
        for (int p = 0; p < 16; ++p) {
            half8 h = *(const half8*)&kl[t][p * 8];
            #pragma unroll
            for (int e = 0; e < 8; ++e) {
                float x = (float)h[e];
                ss = fmaf(x, x, ss);
            }
        }
        rk[t] = 1.0f / fmaxf(sqrtf(ss), 1e-12f);
        bj[t] = (k_mask[o * LK + t] != 0) ? -1e30f : 0.0f;
    }
    // no barrier needed yet: first loop iteration syncs before use

    const float scale  = fminf(__expf(logit_scale[0]), 100.0f);
    const float inv_ln = 1.0f / (sqrtf((float)(LQ * LK)) + 1e-6f);

    // ---- 4. per live b ----
    for (int m = 0; m < M; ++m) {
        const int b = lbm[1 + m];

        // stage q[b] -> f16 LDS
        const float4* qg = (const float4*)(q + (size_t)b * LQ * D_);
        #pragma unroll
        for (int r = 0; r < 4; ++r) {
            int idx = t + 256 * r;                 // float4 index over [32][32]
            float4 v = qg[idx];
            int i = idx >> 5, c4 = idx & 31;
            half4_t h;
            h[0] = (_Float16)v.x; h[1] = (_Float16)v.y;
            h[2] = (_Float16)v.z; h[3] = (_Float16)v.w;
            *(half4_t*)&ql[i][c4 * 4] = h;
        }
        __syncthreads();               // ql (+ rk/bj on first iter) visible

        if (t < LQ) {
            float ss = 0.f;
            #pragma unroll
            for (int p = 0; p < 16; ++p) {
                half8 h = *(const half8*)&ql[t][p * 8];
                #pragma unroll
                for (int e = 0; e < 8; ++e) {
                    float x = (float)h[e];
                    ss = fmaf(x, x, ss);
                }
            }
            rqa[t] = ALPHA / fmaxf(sqrtf(ss), 1e-12f);
        }
        __syncthreads();

        // MFMA: wave w -> rows [16*(w>>1), +16), cols [(w&1)*128, +128)
        const int i0 = (w >> 1) * 16;
        const int j0 = (w & 1) * 128;

        half8 afrag[4];
        #pragma unroll
        for (int kk = 0; kk < 4; ++kk)
            afrag[kk] = *(const half8*)&ql[i0 + row16][kk * 32 + quad * 8];

        float rqv[4];
        #pragma unroll
        for (int rg = 0; rg < 4; ++rg)
            rqv[rg] = rqa[i0 + quad * 4 + rg];

        float esum[4] = {0.f, 0.f, 0.f, 0.f};
        #pragma unroll
        for (int c = 0; c < 8; ++c) {
            const int jt = j0 + c * 16;
            f32x4 acc = {0.f, 0.f, 0.f, 0.f};
            #pragma unroll
            for (int kk = 0; kk < 4; ++kk) {
                half8 bfrag = *(const half8*)&kl[jt + row16][kk * 32 + quad * 8];
                acc = __builtin_amdgcn_mfma_f32_16x16x32_f16(afrag[kk], bfrag,
                                                             acc, 0, 0, 0);
            }
            // C layout: col = lane&15 (j), row = quad*4+reg (i)  [m89/m91]
            const float rkj = rk[jt + row16];
            const float bb  = bj[jt + row16];
            #pragma unroll
            for (int rg = 0; rg < 4; ++rg)
                esum[rg] += __expf(acc[rg] * rqv[rg] * rkj + bb);
        }
        #pragma unroll
        for (int rg = 0; rg < 4; ++rg) {
            float e = esum[rg];
            e += __shfl_xor(e, 1);
            e += __shfl_xor(e, 2);
            e += __shfl_xor(e, 4);
            e += __shfl_xor(e, 8);
            esum[rg] = e;
        }
        if (row16 == 0) {
            #pragma unroll
            for (int rg = 0; rg < 4; ++rg)
                part[w & 1][i0 + quad * 4 + rg] = esum[rg];
        }
        __syncthreads();

        // finalize: wave 0 combines col-halves, log, row-sum, scale
        if (t < 64) {
            float s = 0.f, lse = 0.f;
            bool badrow = false;
            if (t < LQ) {
                s = part[0][t] + part[1][t];
                badrow = (s <= 0.f);               // row fully k-masked -> -inf
                lse = __logf(fmaxf(s, 1e-38f));
            }
            unsigned long long zb = __ballot(badrow);
            float tot = lse;                        // lanes >=32 contribute 0
            tot += __shfl_xor(tot, 32);
            tot += __shfl_xor(tot, 16);
            tot += __shfl_xor(tot, 8);
            tot += __shfl_xor(tot, 4);
            tot += __shfl_xor(tot, 2);
            tot += __shfl_xor(tot, 1);
            if (t == 0) {
                float res = 0.f;
                if (zb == 0ULL)
                    res = (tot * (1.0f / ALPHA)) * inv_ln * scale;
                out[b * O_ + o] = res;
            }
        }
        // next iteration's q staging writes ql only; safe vs. wave-0 finalize
        // (different arrays) and gated by the first in-loop barrier.
    }
}

extern "C" void kernel_launch(void* const* d_in, const int* in_sizes, int n_in,
                              void* d_out, int out_size, void* d_ws, size_t ws_size,
                              hipStream_t stream) {
    const float* q           = (const float*)d_in[0];
    const float* k           = (const float*)d_in[1];
    const int*   q_mask      = (const int*)d_in[2];
    const int*   k_mask      = (const int*)d_in[3];
    const float* logit_scale = (const float*)d_in[4];
    float* out = (float*)d_out;

    colbert_fused_kernel<<<O_, 256, 0, stream>>>(q, k, q_mask, k_mask,
                                                 logit_scale, out);
}